// Round 1
// 451.374 us; speedup vs baseline: 1.0677x; 1.0677x over previous
//
#include <hip/hip_runtime.h>
#include <hip/hip_bf16.h>
#include <math.h>

#define N_NODES 100000
#define N_EDGES 1600000
#define IN_CH 128
#define OUT_CH 128
#define EDGE_DIM 6
#define STATE_DIM 5
#define XS_DIM 133          // IN_CH + STATE_DIM
#define KPAD 160            // 5 k-steps of 32
#define NKSTEP 5
#define ASTRIDE 168         // LDS row stride (bf16 elems)
#define NBLK 391            // ceil(N_NODES/256)
#define N_CHUNKS 25000      // N_EDGES / 64  (exact)

typedef short s16x8 __attribute__((ext_vector_type(8)));
typedef float f32x4 __attribute__((ext_vector_type(4)));

static __device__ __forceinline__ unsigned short f2bf(float f) {
    __hip_bfloat16 h = __float2bfloat16(f);   // RNE
    return *reinterpret_cast<unsigned short*>(&h);
}
static __device__ __forceinline__ float bflo(unsigned u) {   // low bf16 -> f32
    return __uint_as_float(u << 16);
}
static __device__ __forceinline__ float bfhi(unsigned u) {   // high bf16 -> f32
    return __uint_as_float(u & 0xffff0000u);
}

// ---------------------------------------------------------------------------
// Repack W_neg[0:133], W_root into MFMA B-fragment order, bf16, K padded 160.
// ---------------------------------------------------------------------------
__global__ __launch_bounds__(64) void repack_w(
    const float* __restrict__ Wneg, const float* __restrict__ Wroot,
    unsigned short* __restrict__ Pneg, unsigned short* __restrict__ Proot)
{
    int b = blockIdx.x;
    int mat = b / 40, r = b % 40;
    int kk = r / 8, nt = r % 8;
    int lane = threadIdx.x;
    const float* W = mat ? Wroot : Wneg;
    unsigned short* P = mat ? Proot : Pneg;
    int n = nt * 16 + (lane & 15);
    int kb = kk * 32 + (lane >> 4) * 8;
    unsigned short v[8];
#pragma unroll
    for (int j = 0; j < 8; ++j) {
        int k = kb + j;
        v[j] = (k < XS_DIM) ? f2bf(W[k * 128 + n]) : (unsigned short)0;
    }
    *(s16x8*)(P + ((size_t)(kk * 8 + nt) * 64 + lane) * 8) = *(s16x8*)v;
}

// ---------------------------------------------------------------------------
// MFMA node GEMM: 64 nodes/block, 4 waves.
// ---------------------------------------------------------------------------
__global__ __launch_bounds__(256) void node_gemm_mfma(
    const float* __restrict__ x, const float* __restrict__ gs,
    const unsigned short* __restrict__ Pneg, const unsigned short* __restrict__ Proot,
    const float* __restrict__ bneg, const float* __restrict__ broot,
    __hip_bfloat16* __restrict__ Yb, float* __restrict__ out)
{
    __shared__ unsigned short Alds[64 * ASTRIDE];
    const int tid  = threadIdx.x;
    const int lane = tid & 63;
    const int wv   = tid >> 6;
    const int n0   = blockIdx.x * 64;

#pragma unroll
    for (int i = 0; i < 16; ++i) {
        int row = i * 4 + wv;
        int nn  = min(n0 + row, N_NODES - 1);
        const float2 v = *(const float2*)(x + (size_t)nn * IN_CH + lane * 2);
        Alds[row * ASTRIDE + lane * 2]     = f2bf(v.x);
        Alds[row * ASTRIDE + lane * 2 + 1] = f2bf(v.y);
    }
    if (tid < 64) {
        int nn = min(n0 + tid, N_NODES - 1);
#pragma unroll
        for (int j = 0; j < STATE_DIM; ++j)
            Alds[tid * ASTRIDE + IN_CH + j] = f2bf(gs[(size_t)nn * STATE_DIM + j]);
#pragma unroll
        for (int k = XS_DIM; k < KPAD; ++k)
            Alds[tid * ASTRIDE + k] = 0;
    }
    __syncthreads();

    f32x4 accN[8], accR[8];
    const f32x4 zero = {0.f, 0.f, 0.f, 0.f};
#pragma unroll
    for (int nt = 0; nt < 8; ++nt) { accN[nt] = zero; accR[nt] = zero; }

    const int m = lane & 15, quad = lane >> 4;
    const unsigned short* arow = Alds + (wv * 16 + m) * ASTRIDE + quad * 8;

    for (int kk = 0; kk < NKSTEP; ++kk) {
        s16x8 a = *(const s16x8*)(arow + kk * 32);
        const unsigned short* bp = Pneg  + ((size_t)kk * 8 * 64 + lane) * 8;
        const unsigned short* rp = Proot + ((size_t)kk * 8 * 64 + lane) * 8;
#pragma unroll
        for (int nt = 0; nt < 8; ++nt) {
            s16x8 bn = *(const s16x8*)(bp + nt * 512);
            accN[nt] = __builtin_amdgcn_mfma_f32_16x16x32_bf16(a, bn, accN[nt], 0, 0, 0);
            s16x8 br = *(const s16x8*)(rp + nt * 512);
            accR[nt] = __builtin_amdgcn_mfma_f32_16x16x32_bf16(a, br, accR[nt], 0, 0, 0);
        }
    }

#pragma unroll
    for (int nt = 0; nt < 8; ++nt) {
        int col = nt * 16 + m;
        float bn = bneg[col], br = broot[col];
        int rbase = n0 + wv * 16 + quad * 4;
#pragma unroll
        for (int r = 0; r < 4; ++r) {
            int node = rbase + r;
            if (node < N_NODES) {
                Yb[(size_t)node * 128 + col] = __float2bfloat16(accN[nt][r] + bn);
                float v = accR[nt][r] + br;
                out[(size_t)node * 128 + col] = (v > 0.f) ? v : (__expf(v) - 1.f);
            }
        }
    }
}

// ---------------------------------------------------------------------------
// CSR build: memset -> histogram -> 3-pass scan -> payload scatter
// ---------------------------------------------------------------------------
__global__ __launch_bounds__(256) void histogram(const int* __restrict__ idx,
                                                 int* __restrict__ cnt) {
    int e = blockIdx.x * 256 + threadIdx.x;
    if (e < N_EDGES) atomicAdd(&cnt[idx[e]], 1);
}

__global__ __launch_bounds__(256) void scan_block_sums(const int* __restrict__ cnt,
                                                       int* __restrict__ bsum) {
    __shared__ int ws[4];
    int tid = threadIdx.x, lane = tid & 63, wid = tid >> 6;
    int i = blockIdx.x * 256 + tid;
    int v = (i < N_NODES) ? cnt[i] : 0;
#pragma unroll
    for (int d = 32; d > 0; d >>= 1) v += __shfl_down(v, d);
    if (lane == 0) ws[wid] = v;
    __syncthreads();
    if (tid == 0) bsum[blockIdx.x] = ws[0] + ws[1] + ws[2] + ws[3];
}

__global__ __launch_bounds__(512) void scan_bsums(int* __restrict__ bsum) {
    __shared__ int s[512];
    int tid = threadIdx.x;
    int v = (tid < NBLK) ? bsum[tid] : 0;
    s[tid] = v;
    __syncthreads();
    for (int d = 1; d < 512; d <<= 1) {
        int t = (tid >= d) ? s[tid - d] : 0;
        __syncthreads();
        s[tid] += t;
        __syncthreads();
    }
    if (tid < NBLK) bsum[tid] = s[tid] - v;   // exclusive
}

// scan_final additionally fills chunk_node[c] = node containing edge 64*c
// (each 64-edge aggregate chunk's starting node — free here, avoids any
// binary search in aggregate).
__global__ __launch_bounds__(256) void scan_final(const int* __restrict__ cnt,
                                                  const int* __restrict__ bsum,
                                                  int* __restrict__ off,
                                                  int* __restrict__ cursor,
                                                  int* __restrict__ chunk_node) {
    __shared__ int wsum[4];
    int tid = threadIdx.x, lane = tid & 63, wid = tid >> 6;
    int i = blockIdx.x * 256 + tid;
    int v = (i < N_NODES) ? cnt[i] : 0;
    int x = v;
#pragma unroll
    for (int d = 1; d < 64; d <<= 1) {
        int t = __shfl_up(x, d);
        if (lane >= d) x += t;
    }
    if (lane == 63) wsum[wid] = x;
    __syncthreads();
    int wpre = 0;
#pragma unroll
    for (int j = 0; j < 4; ++j) wpre += (j < wid) ? wsum[j] : 0;
    int excl = bsum[blockIdx.x] + wpre + x - v;
    if (i < N_NODES) {
        off[i] = excl; cursor[i] = excl;
        if (v > 0) {
            int end = excl + v;
            for (int c = (excl + 63) >> 6; (c << 6) < end; ++c)
                chunk_node[c] = i;       // chunk start 64c lies inside [excl,end)
        }
    }
}

// payload slot: {src:int, ea packed as 3x(bf16,bf16)} = 16B
__global__ __launch_bounds__(256) void scatter_edges(const int* __restrict__ idx,
                                                     const float* __restrict__ ea,
                                                     int* __restrict__ cursor,
                                                     uint4* __restrict__ pay) {
    int e = blockIdx.x * 256 + threadIdx.x;
    if (e < N_EDGES) {
        int dst = idx[e];
        int src = idx[N_EDGES + e];
        const float* er = ea + (size_t)e * EDGE_DIM;
        unsigned p0 = (unsigned)f2bf(er[0]) | ((unsigned)f2bf(er[1]) << 16);
        unsigned p1 = (unsigned)f2bf(er[2]) | ((unsigned)f2bf(er[3]) << 16);
        unsigned p2 = (unsigned)f2bf(er[4]) | ((unsigned)f2bf(er[5]) << 16);
        int pos = atomicAdd(&cursor[dst], 1);
        uint4 pl = { (unsigned)src, p0, p1, p2 };
        pay[pos] = pl;
    }
}

// ---------------------------------------------------------------------------
// Aggregate, edge-parallel: one wave per 64 consecutive CSR slots (uniform
// work per wave — no degree tail). Segment boundaries via wave-uniform scalar
// walk over off[]; flushes are global f32 atomics into out (deletes the
// 51 MB out read of the node-parallel version). Y-row gathers pipelined 2
// batches (16 edges) ahead in ping-pong register buffers.
// ---------------------------------------------------------------------------
__global__ __launch_bounds__(256) void aggregate(
    const uint4* __restrict__ pay,
    const float* __restrict__ Wneg,  // bottom 6 rows at 133*128
    const __hip_bfloat16* __restrict__ Yb,
    const int* __restrict__ off,
    const int* __restrict__ chunk_node,
    float* __restrict__ out)
{
    const int lane = threadIdx.x & 63;
    const int wid  = __builtin_amdgcn_readfirstlane(blockIdx.x * 4 + (threadIdx.x >> 6));
    const int e0   = wid * 64;

    const float2* wb2 = (const float2*)(Wneg + 133 * 128);
    float2 wb[EDGE_DIM];
#pragma unroll
    for (int j = 0; j < EDGE_DIM; ++j) wb[j] = wb2[j * 64 + lane];

    const unsigned* Yu = (const unsigned*)Yb;   // 64 uints per Y row

    uint4 pl = pay[e0 + lane];                  // coalesced: whole chunk at once
    int src_l = (int)pl.x;
    int ea0 = (int)pl.y, ea1 = (int)pl.z, ea2 = (int)pl.w;

    // wave-uniform segment walk state
    int n   = __builtin_amdgcn_readfirstlane(chunk_node[wid]);
    int nxt = __builtin_amdgcn_readfirstlane((n + 1 < N_NODES) ? off[n + 1] : N_EDGES);

    float accx = 0.f, accy = 0.f;

    // prefetch batches 0 and 1 (16 Y-row loads in flight)
    unsigned yA[8], yB[8];
#pragma unroll
    for (int j = 0; j < 8; ++j) {
        int s = __builtin_amdgcn_readlane(src_l, j);
        yA[j] = Yu[(size_t)s * 64 + lane];
    }
#pragma unroll
    for (int j = 0; j < 8; ++j) {
        int s = __builtin_amdgcn_readlane(src_l, 8 + j);
        yB[j] = Yu[(size_t)s * 64 + lane];
    }

    auto edge_op = [&](unsigned yv, int c, bool last) {
        unsigned a0 = (unsigned)__builtin_amdgcn_readlane(ea0, c);
        unsigned a1 = (unsigned)__builtin_amdgcn_readlane(ea1, c);
        unsigned a2 = (unsigned)__builtin_amdgcn_readlane(ea2, c);
        float f0 = bflo(a0), f1 = bfhi(a0);   // wave-uniform -> SALU shifts
        float f2 = bflo(a1), f3 = bfhi(a1);
        float f4 = bflo(a2), f5 = bfhi(a2);
        float tx = bflo(yv), ty = bfhi(yv);
        tx = fmaf(f0, wb[0].x, tx); ty = fmaf(f0, wb[0].y, ty);
        tx = fmaf(f1, wb[1].x, tx); ty = fmaf(f1, wb[1].y, ty);
        tx = fmaf(f2, wb[2].x, tx); ty = fmaf(f2, wb[2].y, ty);
        tx = fmaf(f3, wb[3].x, tx); ty = fmaf(f3, wb[3].y, ty);
        tx = fmaf(f4, wb[4].x, tx); ty = fmaf(f4, wb[4].y, ty);
        tx = fmaf(f5, wb[5].x, tx); ty = fmaf(f5, wb[5].y, ty);
        tx = (tx > 0.f) ? tx : (__expf(tx) - 1.f);
        ty = (ty > 0.f) ? ty : (__expf(ty) - 1.f);
        accx += tx; accy += ty;
        int e = e0 + c;
        bool bend = (e + 1 == nxt);             // uniform -> s_cmp/s_cbranch
        if (last || bend) {
            float* orow = out + (size_t)n * 128 + (lane << 1);
            atomicAdd(orow,     accx);
            atomicAdd(orow + 1, accy);
            accx = 0.f; accy = 0.f;
            if (!last) {                        // advance to node owning e+1
                n++;
                nxt = __builtin_amdgcn_readfirstlane(
                    (n + 1 < N_NODES) ? off[n + 1] : N_EDGES);
                while (nxt <= e + 1) {          // skip empty nodes (rare)
                    n++;
                    nxt = __builtin_amdgcn_readfirstlane(
                        (n + 1 < N_NODES) ? off[n + 1] : N_EDGES);
                }
            }
        }
    };

    // batches 0..5 with 2-ahead prefetch; tail 6,7 drains
#pragma unroll 1
    for (int q = 0; q < 3; ++q) {
        const int base = q * 16;
        const int pb   = base + 16;             // refill with batch b+2
#pragma unroll
        for (int j = 0; j < 8; ++j) {
            edge_op(yA[j], base + j, false);
            int s = __builtin_amdgcn_readlane(src_l, pb + j);
            yA[j] = Yu[(size_t)s * 64 + lane];
        }
#pragma unroll
        for (int j = 0; j < 8; ++j) {
            edge_op(yB[j], base + 8 + j, false);
            int s = __builtin_amdgcn_readlane(src_l, pb + 8 + j);
            yB[j] = Yu[(size_t)s * 64 + lane];
        }
    }
#pragma unroll
    for (int j = 0; j < 8; ++j) edge_op(yA[j], 48 + j, false);
#pragma unroll
    for (int j = 0; j < 8; ++j) edge_op(yB[j], 56 + j, j == 7);
}

extern "C" void kernel_launch(void* const* d_in, const int* in_sizes, int n_in,
                              void* d_out, int out_size, void* d_ws, size_t ws_size,
                              hipStream_t stream) {
    const float* x     = (const float*)d_in[0];
    const int*   idx   = (const int*)  d_in[1];
    const float* ea    = (const float*)d_in[2];
    const float* gs    = (const float*)d_in[3];
    const float* Wneg  = (const float*)d_in[4];
    const float* bneg  = (const float*)d_in[5];
    const float* Wroot = (const float*)d_in[6];
    const float* broot = (const float*)d_in[7];
    float* out = (float*)d_out;

    // ws layout (16B-aligned sections):
    //   Yb      : N*128 bf16           25.6 MB
    //   cnt/off/cur : N int each        1.2 MB
    //   bsum    : NBLK int (pad 2KB)
    //   pay     : E * 16B              25.6 MB
    //   Pneg/Proot : 40 KB each
    //   chunk_node : 25000 int         100 KB
    char* w = (char*)d_ws;
    __hip_bfloat16* Yb = (__hip_bfloat16*)w;      w += (size_t)N_NODES * 128 * 2;
    int* cnt  = (int*)w;                          w += (size_t)N_NODES * 4;
    int* off  = (int*)w;                          w += (size_t)N_NODES * 4;
    int* cur  = (int*)w;                          w += (size_t)N_NODES * 4;
    int* bsum = (int*)w;                          w += 2048;
    uint4* pay = (uint4*)w;                       w += (size_t)N_EDGES * 16;
    unsigned short* Pneg  = (unsigned short*)w;   w += (size_t)NKSTEP * 8 * 64 * 8 * 2;
    unsigned short* Proot = (unsigned short*)w;   w += (size_t)NKSTEP * 8 * 64 * 8 * 2;
    int* chunk_node = (int*)w;

    const int nb_edges = (N_EDGES + 255) / 256;

    repack_w<<<80, 64, 0, stream>>>(Wneg, Wroot, Pneg, Proot);
    node_gemm_mfma<<<(N_NODES + 63) / 64, 256, 0, stream>>>(
        x, gs, Pneg, Proot, bneg, broot, Yb, out);
    hipMemsetAsync(cnt, 0, (size_t)N_NODES * 4, stream);
    histogram<<<nb_edges, 256, 0, stream>>>(idx, cnt);
    scan_block_sums<<<NBLK, 256, 0, stream>>>(cnt, bsum);
    scan_bsums<<<1, 512, 0, stream>>>(bsum);
    scan_final<<<NBLK, 256, 0, stream>>>(cnt, bsum, off, cur, chunk_node);
    scatter_edges<<<nb_edges, 256, 0, stream>>>(idx, ea, cur, pay);
    aggregate<<<N_CHUNKS / 4, 256, 0, stream>>>(pay, Wneg, Yb, off, chunk_node, out);
}